// Round 11
// baseline (320.147 us; speedup 1.0000x reference)
//
#include <hip/hip_runtime.h>

// LearnableGlobalLocalMultiheadAttention — round 11: single-pass phase 4 with
// capped unroll (the no-spill version of r9's fastest-attn structure).
//
// Algorithmic core (verified r1-10): triu*mini = kron(triu32,triu32)
// =>  A @ triu   == 2D inclusive prefix-sum of each row viewed as [32][32]
//     A @ triu^T == suffix sum; after softmax the 2D total == 1.0 exactly.
//
// Round 11 change (r9 vs r10 attribution: r9 single-pass @ full unroll spilled
// (16 hoisted v8h B-operands = 64 VGPRs) yet ran 157 us; r10 two-pass was
// spill-free but de-interleaved MFMAs from edge reads + register-starved
// codegen -> VALU issue 72->102 us*CU, 187 us. Best of both:)
//   phase 4 = single pass (MFMA-interleaved edge reads, sc4[8] sole
//   cross-barrier state, mk -> pmask direct, TL/TR = 1.0) with
//   #pragma unroll 2 so only 4 B-operands (16 VGPRs) are in flight.
//   Everything else identical to r10.

typedef _Float16 v8h __attribute__((ext_vector_type(8)));
typedef _Float16 v4h __attribute__((ext_vector_type(4)));
typedef _Float16 v2h __attribute__((ext_vector_type(2)));
typedef float    v4f __attribute__((ext_vector_type(4)));

#define SL 1048576   // halves per packed slice (32 bh * 1024 * 32)
#define RS 1032      // LDS row stride in fp16 elems (1024 + 8 pad)

static constexpr float SCALE = 0.17677669529663687f; // 32^-0.5

// ws layout (bytes):
//   [0, 18874368)         : 9 packed fp16 slices, slice i at i*SL halves
//       q-type {0,3,5,7} / k-type {1,4,6,8}: [bh][tile(64)][lane(64)][8]
//       slice 2 (v), PV-B: [bh][kc(32)][nt(2)][lane(64)][8]
//   [18874368, +4 MB)     : attn_pre fp32 [4096][256]
//   [23068672, +64 MB)    : pmask fp16 [32][64 rt][16384] fragment order:
//                           half index = jt*256 + lane*4 + i
//   [90177536, +6 MB)     : X16 fp16 {q,k,v} [4096][256] each
//   [96468992, +1.2 MB)   : W16 fp16 [2304][256]

// ---------------- Kernel 0: fp32 -> fp16 conversion ----------------
__global__ __launch_bounds__(256)
void cvt_kernel(const float* __restrict__ q, const float* __restrict__ k,
                const float* __restrict__ v, const float* __restrict__ W,
                _Float16* __restrict__ X16, _Float16* __restrict__ W16)
{
    const int b = blockIdx.x;
    const int t = threadIdx.x;
    const float* src; _Float16* dst; int off;
    if (b < 512)       { src = q; dst = X16;             off = b; }
    else if (b < 1024) { src = k; dst = X16 + (1 << 20); off = b - 512; }
    else if (b < 1536) { src = v; dst = X16 + (2 << 20); off = b - 1024; }
    else               { src = W; dst = W16;             off = b - 1536; }
    const int i = off * 2048 + t * 8;
    const float4 a = *(const float4*)(src + i);
    const float4 c = *(const float4*)(src + i + 4);
    v8h h;
    h[0] = (_Float16)a.x; h[1] = (_Float16)a.y; h[2] = (_Float16)a.z; h[3] = (_Float16)a.w;
    h[4] = (_Float16)c.x; h[5] = (_Float16)c.y; h[6] = (_Float16)c.z; h[7] = (_Float16)c.w;
    *(v8h*)(dst + i) = h;
}

// ---------------- Kernel 1: packed input projection (fp16 MFMA) ----------------
__global__ __launch_bounds__(256)
void proj_kernel(const _Float16* __restrict__ X16, const _Float16* __restrict__ W16,
                 const float* __restrict__ bias, _Float16* __restrict__ P)
{
    const int t  = threadIdx.x;
    const int n0 = blockIdx.x * 64;   // output column tile (0..2303)
    const int m0 = blockIdx.y * 64;   // row tile (0..4095), row = s*4 + b
    const int slice = n0 >> 8;        // uniform per block
    const bool kslice = (slice == 1) || (slice == 4) || (slice == 6) || (slice == 8);
    const _Float16* X = X16 + (slice == 2 ? (2 << 20) : (kslice ? (1 << 20) : 0));
    const int w = t >> 6, lane = t & 63, m16 = lane & 15, kg = lane >> 4;
    const v4f zero = {0.f, 0.f, 0.f, 0.f};
    v4f acc[4] = {zero, zero, zero, zero};
    const _Float16* Arow = X + (size_t)(m0 + w * 16 + m16) * 256 + kg * 8;
    const _Float16* B0   = W16 + (size_t)(n0 + m16) * 256 + kg * 8;
#pragma unroll
    for (int kk = 0; kk < 8; ++kk) {
        const v8h a = *(const v8h*)(Arow + kk * 32);
#pragma unroll
        for (int nf = 0; nf < 4; ++nf) {
            const v8h bb = *(const v8h*)(B0 + nf * 4096 + kk * 32);
            acc[nf] = __builtin_amdgcn_mfma_f32_16x16x32_f16(a, bb, acc[nf], 0, 0, 0);
        }
    }
    const float scale = (slice == 0 || slice == 7) ? SCALE : 1.0f;
#pragma unroll
    for (int nf = 0; nf < 4; ++nf) {
        const int c = n0 + nf * 16 + m16;
        const float bv = bias[c];
        const int cc = c & 255;
        const int h = cc >> 5, d = cc & 31;
#pragma unroll
        for (int i = 0; i < 4; ++i) {
            const int m = m0 + w * 16 + kg * 4 + i;
            const int s = m >> 2, bs = m & 3;
            const int bh = bs * 8 + h;
            const float val = (acc[nf][i] + bv) * scale;
            size_t addr;
            if (slice == 2) {
                const int kc = s >> 5, kgv = (s >> 3) & 3, jj = s & 7;
                const int nt = d >> 4, nn = d & 15;
                addr = (size_t)2 * SL + (size_t)bh * 32768
                     + (size_t)((((kc << 1) + nt) << 6) + (nn + (kgv << 4))) * 8 + jj;
            } else {
                const int tile = s >> 4, mm = s & 15, kg8 = d >> 3, jj = d & 7;
                addr = (size_t)slice * SL + (size_t)bh * 32768
                     + (size_t)((tile << 6) + (mm + (kg8 << 4))) * 8 + jj;
            }
            P[addr] = (_Float16)val;
        }
    }
}

// ---------------- Kernel 2: fused MFMA attention ----------------
// 2048 blocks x 512 threads (8 waves): xcd = bid&7, q = bid>>3;
// bh = xcd*4 + (q&3), rt = q>>2. (512,4): 16 waves/CU. Phase 4 single-pass
// with unroll 2 (4 B-operands in flight) -> fits 128 unified regs, no spill.
__global__ __launch_bounds__(512, 4)
void attn_kernel(const _Float16* __restrict__ P, float* __restrict__ attn_pre,
                 _Float16* __restrict__ pmask)
{
    __shared__ __align__(16) _Float16 Lh[16 * RS];
    __shared__ __align__(16) _Float16 Rh[16 * RS];

    const int t    = threadIdx.x;
    const int bid  = blockIdx.x;
    const int q    = bid >> 3;
    const int bh   = ((bid & 7) << 2) + (q & 3);
    const int rt   = q >> 2;
    const int w    = __builtin_amdgcn_readfirstlane(t >> 6);
    const int lane = t & 63;
    const int m16  = lane & 15;
    const int kg   = lane >> 4;

    const _Float16* Pb = P + (size_t)bh * 32768;
    const v4f zero = {0.f, 0.f, 0.f, 0.f};

    // ---- Phase 1: left/right logits via MFMA -> LDS fp16 ----
    {
        const v8h a_l = *(const v8h*)(Pb + 3 * SL + rt * 512 + lane * 8);
        const v8h a_r = *(const v8h*)(Pb + 5 * SL + rt * 512 + lane * 8);
        const _Float16* Bl = Pb + 4 * SL;
        const _Float16* Br = Pb + 6 * SL;
#pragma unroll 4
        for (int jt2 = 0; jt2 < 8; ++jt2) {
            const int jt = (w << 3) + jt2;
            const v8h bL = *(const v8h*)(Bl + jt * 512 + lane * 8);
            const v8h bR = *(const v8h*)(Br + jt * 512 + lane * 8);
            v4f cL = __builtin_amdgcn_mfma_f32_16x16x32_f16(a_l, bL, zero, 0, 0, 0);
            v4f cR = __builtin_amdgcn_mfma_f32_16x16x32_f16(a_r, bR, zero, 0, 0, 0);
            const int col = (jt << 4) + m16;
#pragma unroll
            for (int i = 0; i < 4; ++i) {
                Lh[((kg << 2) + i) * RS + col] = (_Float16)cL[i];
                Rh[((kg << 2) + i) * RS + col] = (_Float16)cR[i];
            }
        }
    }
    __syncthreads();

    // ---- Phase 2: softmax per row, no max pass (logits O(+-15), fp32 exp) ----
    auto softmax_pairs = [&](_Float16* ROW) {
        float v0[8], v1[8];
        float ss = 0.f;
#pragma unroll
        for (int kq = 0; kq < 8; ++kq) {
            const v2h pr = *(const v2h*)&ROW[(lane + (kq << 6)) << 1];
            v0[kq] = __expf((float)pr[0]);
            v1[kq] = __expf((float)pr[1]);
            ss += v0[kq] + v1[kq];
        }
#pragma unroll
        for (int off = 32; off; off >>= 1) ss += __shfl_xor(ss, off);
        const float inv = 1.f / ss;
#pragma unroll
        for (int kq = 0; kq < 8; ++kq) {
            v2h pr; pr[0] = (_Float16)(v0[kq] * inv); pr[1] = (_Float16)(v1[kq] * inv);
            *(v2h*)&ROW[(lane + (kq << 6)) << 1] = pr;
        }
    };
#pragma unroll
    for (int r = 0; r < 2; ++r) {
        softmax_pairs(&Lh[((w << 1) + r) * RS]);
        softmax_pairs(&Rh[((w << 1) + r) * RS]);
    }
    // no barrier: phase 3 touches the same rows from the same wave.

    // ---- Phase 3: fused 2D inclusive prefix scan (lanes<32: L, >=32: R) ----
    {
        const int kr = lane & 31;
#pragma unroll
        for (int r = 0; r < 2; ++r) {
            _Float16* ROW = (lane >= 32) ? &Rh[((w << 1) + r) * RS] : &Lh[((w << 1) + r) * RS];
            float run = 0.f;
#pragma unroll 4
            for (int kb = 0; kb < 32; ++kb) {
                float x = (float)ROW[(kb << 5) + kr];
#pragma unroll
                for (int off = 1; off < 32; off <<= 1) {
                    float y = __shfl_up(x, off, 32);
                    if (kr >= off) x += y;
                }
                run += x;                       // P(kb,kr)
                ROW[(kb << 5) + kr] = (_Float16)run;
            }
        }
    }
    __syncthreads();

    // ---- Phase 4: single pass — g/c MFMAs interleaved with mask combine.
    // sc4[8] = sole cross-barrier state; mk -> pmask direct; 2D total == 1.0.
    // unroll 2: only 4 v8h B-operands hoisted (16 VGPRs) -> no spill at (512,4).
    v4h sc4[8];
    {
        _Float16* pm = pmask + (size_t)bh * 1048576 + (size_t)rt * 16384;
        const v8h a_g = *(const v8h*)(Pb + 0 * SL + rt * 512 + lane * 8);
        const v8h a_c = *(const v8h*)(Pb + 7 * SL + rt * 512 + lane * 8);
        const _Float16* Bg = Pb + 1 * SL;
        const _Float16* Bc = Pb + 8 * SL;
#pragma unroll 2
        for (int jt2 = 0; jt2 < 8; ++jt2) {
            const int jt  = (w << 3) + jt2;
            const int jb  = jt >> 1;
            const int jr  = ((jt & 1) << 4) + m16;
            const int col = (jt << 4) + m16;
            const v8h bG = *(const v8h*)(Bg + jt * 512 + lane * 8);
            const v8h bC = *(const v8h*)(Bc + jt * 512 + lane * 8);
            const v4f g4 = __builtin_amdgcn_mfma_f32_16x16x32_f16(a_g, bG, zero, 0, 0, 0);
            const v4f l4 = __builtin_amdgcn_mfma_f32_16x16x32_f16(a_c, bC, zero, 0, 0, 0);
            v4h s4, m4;
#pragma unroll
            for (int i = 0; i < 4; ++i) {
                const int rr = ((kg << 2) + i) * RS;
                const float PL  = (float)Lh[rr + col];
                const float PR  = (float)Rh[rr + col];
                const float eLb = jb ? (float)Lh[rr + (jb << 5) - 1] : 0.f;
                const float eRb = jb ? (float)Rh[rr + (jb << 5) - 1] : 0.f;
                const float eLc = jr ? (float)Lh[rr + 991 + jr] : 0.f;
                const float eRc = jr ? (float)Rh[rr + 991 + jr] : 0.f;
                const float eLbc = (jb && jr) ? (float)Lh[rr + ((jb - 1) << 5) + jr - 1] : 0.f;
                const float eRbc = (jb && jr) ? (float)Rh[rr + ((jb - 1) << 5) + jr - 1] : 0.f;
                const float SLv = 1.0f - eLb - eLc + eLbc;
                const float SRv = 1.0f - eRb - eRc + eRbc;
                const float mkv = PL * SRv + SLv * PR;
                s4[i] = (_Float16)(0.1f * g4[i] + l4[i] * mkv);
                m4[i] = (_Float16)mkv;
            }
            sc4[jt2] = s4;
            *(v4h*)(pm + ((size_t)jt << 8) + (lane << 2)) = m4;   // coalesced 8 B/lane
        }
    }
    __syncthreads();   // all scan reads complete before overwrite

    // ---- Phase 4b: write S -> Lh ----
    {
#pragma unroll
        for (int jt2 = 0; jt2 < 8; ++jt2) {
            const int col = ((((w << 3) + jt2)) << 4) + m16;
#pragma unroll
            for (int i = 0; i < 4; ++i)
                Lh[((kg << 2) + i) * RS + col] = sc4[jt2][i];
        }
    }
    __syncthreads();

    // ---- Phase 5: final softmax on S ----
#pragma unroll
    for (int r = 0; r < 2; ++r) softmax_pairs(&Lh[((w << 1) + r) * RS]);
    __syncthreads();

    // ---- Phase 6: PV via MFMA. wave = (nt = d-half, hf = j-quarter) ----
    {
        const int nt = w & 1, hf = w >> 1;
        v4f c = zero;
        const _Float16* Vb = Pb + 2 * SL + nt * 512 + lane * 8;
        const int kc0 = hf << 3;
#pragma unroll 4
        for (int kc2 = 0; kc2 < 8; ++kc2) {
            const int kc = kc0 + kc2;
            const v8h a = *(const v8h*)&Lh[m16 * RS + (kc << 5) + (kg << 3)];
            const v8h b = *(const v8h*)(Vb + (size_t)kc * 1024);
            c = __builtin_amdgcn_mfma_f32_16x16x32_f16(a, b, c, 0, 0, 0);
        }
        float* Pbuf = (float*)&Rh[0];   // Rh dead since phase-4 barrier
#pragma unroll
        for (int i = 0; i < 4; ++i) Pbuf[(w << 8) + (lane << 2) + i] = c[i];
    }
    __syncthreads();

    // ---- Epilogue: fold 4 j-quarters, coalesced d-fastest store ----
    {
        const float* Pbuf = (const float*)&Rh[0];
        const int r   = t >> 5;                    // row in tile (0..15)
        const int d   = t & 31;
        const int nt2 = d >> 4, n = d & 15;
        const int kg2 = r >> 2, i2 = r & 3;
        const int off = (kg2 << 6) + (n << 2) + i2;   // lane*4 + i
        float v = 0.f;
#pragma unroll
        for (int hf = 0; hf < 4; ++hf)
            v += Pbuf[(((hf << 1) + nt2) << 8) + off];
        const int srow = (rt << 4) + r;
        attn_pre[((size_t)(srow * 4 + (bh >> 3))) * 256 + (bh & 7) * 32 + d] = v;
    }
}

// ---------------- Kernel 2b: 32-way pmask reduction (fragment order) ----------------
__global__ __launch_bounds__(256)
void cmask_reduce_kernel(const _Float16* __restrict__ pmask, float* __restrict__ cmask)
{
    __shared__ float T[16][516];
    const int rt = blockIdx.x, wh = blockIdx.y;
    const int t = threadIdx.x;
    const int w = (wh << 2) + (t >> 6);
    const int lane = t & 63, m16 = lane & 15, kg = lane >> 4;
    float acc[8][4] = {};
    const _Float16* base = pmask + (size_t)rt * 16384 + ((size_t)w << 11) + (lane << 2);
    for (int bh = 0; bh < 32; ++bh) {
        const _Float16* p = base + (size_t)bh * 1048576;
#pragma unroll
        for (int jt2 = 0; jt2 < 8; ++jt2) {
            const v4h h4 = *(const v4h*)(p + (jt2 << 8));
#pragma unroll
            for (int i = 0; i < 4; ++i) acc[jt2][i] += (float)h4[i];
        }
    }
#pragma unroll
    for (int jt2 = 0; jt2 < 8; ++jt2)
#pragma unroll
        for (int i = 0; i < 4; ++i)
            T[(kg << 2) + i][((w & 3) << 7) + (jt2 << 4) + m16] = acc[jt2][i];
    __syncthreads();
#pragma unroll
    for (int p8 = 0; p8 < 8; ++p8) {
        const int idx = (p8 << 8) + t;             // 0..2047
        const int row = idx >> 7, cq = idx & 127;
        const int c0 = (cq << 2);
        float4 o = *(const float4*)&T[row][c0];
        *(float4*)&cmask[((size_t)((rt << 4) + row) << 10) + (wh << 9) + c0] = o;
    }
}

// ---------------- Kernel 3: output projection (fp32) ----------------
__global__ __launch_bounds__(256)
void outproj_kernel(const float* __restrict__ A, const float* __restrict__ W,
                    const float* __restrict__ bias, float* __restrict__ C)
{
    __shared__ float As[16][68];
    __shared__ float Bs[16][68];
    const int t  = threadIdx.x;
    const int n0 = blockIdx.x * 64;
    const int m0 = blockIdx.y * 64;
    const int tx = t & 15, ty = t >> 4;
    const int lm = t >> 2, lk = (t & 3) << 2;
    float acc[4][4] = {};
    for (int k0 = 0; k0 < 256; k0 += 16) {
        float4 av = *(const float4*)(A + (size_t)(m0 + lm) * 256 + k0 + lk);
        float4 bv = *(const float4*)(W + (size_t)(n0 + lm) * 256 + k0 + lk);
        As[lk + 0][lm] = av.x; As[lk + 1][lm] = av.y; As[lk + 2][lm] = av.z; As[lk + 3][lm] = av.w;
        Bs[lk + 0][lm] = bv.x; Bs[lk + 1][lm] = bv.y; Bs[lk + 2][lm] = bv.z; Bs[lk + 3][lm] = bv.w;
        __syncthreads();
#pragma unroll
        for (int kk = 0; kk < 16; ++kk) {
            float4 a4 = *(const float4*)&As[kk][ty << 2];
            float4 b4 = *(const float4*)&Bs[kk][tx << 2];
            float aa[4] = {a4.x, a4.y, a4.z, a4.w};
            float bb[4] = {b4.x, b4.y, b4.z, b4.w};
#pragma unroll
            for (int i = 0; i < 4; ++i)
#pragma unroll
                for (int j = 0; j < 4; ++j)
                    acc[i][j] = fmaf(aa[i], bb[j], acc[i][j]);
        }
        __syncthreads();
    }
#pragma unroll
    for (int i = 0; i < 4; ++i) {
        const int m  = m0 + (ty << 2) + i;
        const int c0 = n0 + (tx << 2);
        float4 o = make_float4(acc[i][0] + bias[c0 + 0], acc[i][1] + bias[c0 + 1],
                               acc[i][2] + bias[c0 + 2], acc[i][3] + bias[c0 + 3]);
        *(float4*)&C[(size_t)m * 256 + c0] = o;
    }
}

extern "C" void kernel_launch(void* const* d_in, const int* in_sizes, int n_in,
                              void* d_out, int out_size, void* d_ws, size_t ws_size,
                              hipStream_t stream)
{
    const float* q  = (const float*)d_in[0];
    const float* k  = (const float*)d_in[1];
    const float* v  = (const float*)d_in[2];
    const float* Wi = (const float*)d_in[3];
    const float* bi = (const float*)d_in[4];
    const float* Wo = (const float*)d_in[5];
    const float* bo = (const float*)d_in[6];

    float* out      = (float*)d_out;
    float* attn_out = out;                 // [1024,4,256]
    float* cmask    = out + 1048576;       // [1024,1024]

    _Float16* Ppack    = (_Float16*)d_ws;
    float*    attn_pre = (float*)((char*)d_ws + 18874368);
    _Float16* pmask    = (_Float16*)((char*)d_ws + 23068672);
    _Float16* X16      = (_Float16*)((char*)d_ws + 90177536);
    _Float16* W16      = (_Float16*)((char*)d_ws + 96468992);

    cvt_kernel<<<1824, 256, 0, stream>>>(q, k, v, Wi, X16, W16);
    proj_kernel<<<dim3(36, 64), 256, 0, stream>>>(X16, W16, bi, Ppack);
    attn_kernel<<<2048, 512, 0, stream>>>(Ppack, attn_pre, pmask);
    cmask_reduce_kernel<<<dim3(64, 2), 256, 0, stream>>>(pmask, cmask);
    outproj_kernel<<<dim3(4, 64), 256, 0, stream>>>(attn_pre, Wo, bo, attn_out);
}

// Round 12
// 293.114 us; speedup vs baseline: 1.0922x; 1.0922x over previous
//
#include <hip/hip_runtime.h>

// LearnableGlobalLocalMultiheadAttention — round 12: recombine measured-best
// components. attn = r9 verbatim (157 us measured); non-attn = r8 verbatim
// (~115 us measured as a set).
//
// Algorithmic core (verified r1-11): triu*mini = kron(triu32,triu32)
// =>  A @ triu   == 2D inclusive prefix-sum of each row viewed as [32][32]
//     A @ triu^T == suffix sum; after softmax the 2D total == 1.0 exactly.
//
// Attribution from r9/r10/r11 A/B/C on phase 4:
//   full unroll + spills (r9) 157 << two-pass no-spill (r10) 187
//   << unroll-2 no-spill (r11) 203.
// Mechanism: full unroll issues all 16 B-operand global loads up front (MLP);
// one vmcnt covers them all. Scratch spill traffic (~270 MB) is VMEM, overlaps
// at 16 waves/CU, and costs less than the serialized load round-trips of the
// partial unrolls. Spill-avoidance was a proxy metric; wall-clock wins.

typedef _Float16 v8h __attribute__((ext_vector_type(8)));
typedef _Float16 v4h __attribute__((ext_vector_type(4)));
typedef _Float16 v2h __attribute__((ext_vector_type(2)));
typedef float    v4f __attribute__((ext_vector_type(4)));

#define SL 1048576   // halves per packed slice (32 bh * 1024 * 32)
#define RS 1032      // LDS row stride in fp16 elems (1024 + 8 pad)

static constexpr float SCALE = 0.17677669529663687f; // 32^-0.5

// ws layout (bytes):
//   [0, 18874368)         : 9 packed fp16 slices, slice i at i*SL halves
//       q-type {0,3,5,7} / k-type {1,4,6,8}: [bh][tile(64)][lane(64)][8]
//       slice 2 (v), PV-B: [bh][kc(32)][nt(2)][lane(64)][8]
//   [18874368, +4 MB)     : attn_pre fp32 [4096][256]
//   [23068672, +64 MB)    : pmask fp16 [32][64 rt][16384] fragment order:
//                           half index = jt*256 + lane*4 + i
//   [90177536, +6 MB)     : X16 fp16 {q,k,v} [4096][256] each
//   [96468992, +1.2 MB)   : W16 fp16 [2304][256]

// ---------------- Kernel 0: fp32 -> fp16 conversion (r8) ----------------
__global__ __launch_bounds__(256)
void cvt_kernel(const float* __restrict__ q, const float* __restrict__ k,
                const float* __restrict__ v, const float* __restrict__ W,
                _Float16* __restrict__ X16, _Float16* __restrict__ W16)
{
    const int b = blockIdx.x;
    const int t = threadIdx.x;
    const float* src; _Float16* dst; int off;
    if (b < 512)       { src = q; dst = X16;             off = b; }
    else if (b < 1024) { src = k; dst = X16 + (1 << 20); off = b - 512; }
    else if (b < 1536) { src = v; dst = X16 + (2 << 20); off = b - 1024; }
    else               { src = W; dst = W16;             off = b - 1536; }
    const int i = off * 2048 + t * 8;
    const float4 a = *(const float4*)(src + i);
    const float4 c = *(const float4*)(src + i + 4);
    v8h h;
    h[0] = (_Float16)a.x; h[1] = (_Float16)a.y; h[2] = (_Float16)a.z; h[3] = (_Float16)a.w;
    h[4] = (_Float16)c.x; h[5] = (_Float16)c.y; h[6] = (_Float16)c.z; h[7] = (_Float16)c.w;
    *(v8h*)(dst + i) = h;
}

// ---------------- Kernel 1: packed input projection (fp16 MFMA, r8) ----------------
__global__ __launch_bounds__(256)
void proj_kernel(const _Float16* __restrict__ X16, const _Float16* __restrict__ W16,
                 const float* __restrict__ bias, _Float16* __restrict__ P)
{
    const int t  = threadIdx.x;
    const int n0 = blockIdx.x * 64;   // output column tile (0..2303)
    const int m0 = blockIdx.y * 64;   // row tile (0..4095), row = s*4 + b
    const int slice = n0 >> 8;        // uniform per block
    const bool kslice = (slice == 1) || (slice == 4) || (slice == 6) || (slice == 8);
    const _Float16* X = X16 + (slice == 2 ? (2 << 20) : (kslice ? (1 << 20) : 0));
    const int w = t >> 6, lane = t & 63, m16 = lane & 15, kg = lane >> 4;
    const v4f zero = {0.f, 0.f, 0.f, 0.f};
    v4f acc[4] = {zero, zero, zero, zero};
    const _Float16* Arow = X + (size_t)(m0 + w * 16 + m16) * 256 + kg * 8;
    const _Float16* B0   = W16 + (size_t)(n0 + m16) * 256 + kg * 8;
#pragma unroll
    for (int kk = 0; kk < 8; ++kk) {
        const v8h a = *(const v8h*)(Arow + kk * 32);
#pragma unroll
        for (int nf = 0; nf < 4; ++nf) {
            const v8h bb = *(const v8h*)(B0 + nf * 4096 + kk * 32);
            acc[nf] = __builtin_amdgcn_mfma_f32_16x16x32_f16(a, bb, acc[nf], 0, 0, 0);
        }
    }
    const float scale = (slice == 0 || slice == 7) ? SCALE : 1.0f;
#pragma unroll
    for (int nf = 0; nf < 4; ++nf) {
        const int c = n0 + nf * 16 + m16;
        const float bv = bias[c];
        const int cc = c & 255;
        const int h = cc >> 5, d = cc & 31;
#pragma unroll
        for (int i = 0; i < 4; ++i) {
            const int m = m0 + w * 16 + kg * 4 + i;
            const int s = m >> 2, bs = m & 3;
            const int bh = bs * 8 + h;
            const float val = (acc[nf][i] + bv) * scale;
            size_t addr;
            if (slice == 2) {
                const int kc = s >> 5, kgv = (s >> 3) & 3, jj = s & 7;
                const int nt = d >> 4, nn = d & 15;
                addr = (size_t)2 * SL + (size_t)bh * 32768
                     + (size_t)((((kc << 1) + nt) << 6) + (nn + (kgv << 4))) * 8 + jj;
            } else {
                const int tile = s >> 4, mm = s & 15, kg8 = d >> 3, jj = d & 7;
                addr = (size_t)slice * SL + (size_t)bh * 32768
                     + (size_t)((tile << 6) + (mm + (kg8 << 4))) * 8 + jj;
            }
            P[addr] = (_Float16)val;
        }
    }
}

// ---------------- Kernel 2: fused MFMA attention (r9 verbatim) ----------------
// 2048 blocks x 512 threads (8 waves): xcd = bid&7, q = bid>>3;
// bh = xcd*4 + (q&3), rt = q>>2. (512,4): 16 waves/CU. Phase 4 single-pass,
// FULL unroll (16 B-operand loads in flight — the measured-fastest variant;
// the resulting scratch spills are an accepted trade for load MLP).
__global__ __launch_bounds__(512, 4)
void attn_kernel(const _Float16* __restrict__ P, float* __restrict__ attn_pre,
                 _Float16* __restrict__ pmask)
{
    __shared__ __align__(16) _Float16 Lh[16 * RS];
    __shared__ __align__(16) _Float16 Rh[16 * RS];

    const int t    = threadIdx.x;
    const int bid  = blockIdx.x;
    const int q    = bid >> 3;
    const int bh   = ((bid & 7) << 2) + (q & 3);
    const int rt   = q >> 2;
    const int w    = __builtin_amdgcn_readfirstlane(t >> 6);
    const int lane = t & 63;
    const int m16  = lane & 15;
    const int kg   = lane >> 4;

    const _Float16* Pb = P + (size_t)bh * 32768;
    const v4f zero = {0.f, 0.f, 0.f, 0.f};

    // ---- Phase 1: left/right logits via MFMA -> LDS fp16 ----
    {
        const v8h a_l = *(const v8h*)(Pb + 3 * SL + rt * 512 + lane * 8);
        const v8h a_r = *(const v8h*)(Pb + 5 * SL + rt * 512 + lane * 8);
        const _Float16* Bl = Pb + 4 * SL;
        const _Float16* Br = Pb + 6 * SL;
#pragma unroll 4
        for (int jt2 = 0; jt2 < 8; ++jt2) {
            const int jt = (w << 3) + jt2;
            const v8h bL = *(const v8h*)(Bl + jt * 512 + lane * 8);
            const v8h bR = *(const v8h*)(Br + jt * 512 + lane * 8);
            v4f cL = __builtin_amdgcn_mfma_f32_16x16x32_f16(a_l, bL, zero, 0, 0, 0);
            v4f cR = __builtin_amdgcn_mfma_f32_16x16x32_f16(a_r, bR, zero, 0, 0, 0);
            const int col = (jt << 4) + m16;
#pragma unroll
            for (int i = 0; i < 4; ++i) {
                Lh[((kg << 2) + i) * RS + col] = (_Float16)cL[i];
                Rh[((kg << 2) + i) * RS + col] = (_Float16)cR[i];
            }
        }
    }
    __syncthreads();

    // ---- Phase 2: softmax per row, no max pass (logits O(+-15), fp32 exp) ----
    auto softmax_pairs = [&](_Float16* ROW) {
        float v0[8], v1[8];
        float ss = 0.f;
#pragma unroll
        for (int kq = 0; kq < 8; ++kq) {
            const v2h pr = *(const v2h*)&ROW[(lane + (kq << 6)) << 1];
            v0[kq] = __expf((float)pr[0]);
            v1[kq] = __expf((float)pr[1]);
            ss += v0[kq] + v1[kq];
        }
#pragma unroll
        for (int off = 32; off; off >>= 1) ss += __shfl_xor(ss, off);
        const float inv = 1.f / ss;
#pragma unroll
        for (int kq = 0; kq < 8; ++kq) {
            v2h pr; pr[0] = (_Float16)(v0[kq] * inv); pr[1] = (_Float16)(v1[kq] * inv);
            *(v2h*)&ROW[(lane + (kq << 6)) << 1] = pr;
        }
    };
#pragma unroll
    for (int r = 0; r < 2; ++r) {
        softmax_pairs(&Lh[((w << 1) + r) * RS]);
        softmax_pairs(&Rh[((w << 1) + r) * RS]);
    }
    // no barrier: phase 3 touches the same rows from the same wave.

    // ---- Phase 3: fused 2D inclusive prefix scan (lanes<32: L, >=32: R) ----
    {
        const int kr = lane & 31;
#pragma unroll
        for (int r = 0; r < 2; ++r) {
            _Float16* ROW = (lane >= 32) ? &Rh[((w << 1) + r) * RS] : &Lh[((w << 1) + r) * RS];
            float run = 0.f;
#pragma unroll 4
            for (int kb = 0; kb < 32; ++kb) {
                float x = (float)ROW[(kb << 5) + kr];
#pragma unroll
                for (int off = 1; off < 32; off <<= 1) {
                    float y = __shfl_up(x, off, 32);
                    if (kr >= off) x += y;
                }
                run += x;                       // P(kb,kr)
                ROW[(kb << 5) + kr] = (_Float16)run;
            }
        }
    }
    __syncthreads();

    // ---- Phase 4: single pass, FULL unroll — g/c MFMAs + mask combine;
    // mk -> pmask direct; sc4 sole cross-barrier state; 2D total == 1.0. ----
    v4h sc4[8];
    {
        _Float16* pm = pmask + (size_t)bh * 1048576 + (size_t)rt * 16384;
        const v8h a_g = *(const v8h*)(Pb + 0 * SL + rt * 512 + lane * 8);
        const v8h a_c = *(const v8h*)(Pb + 7 * SL + rt * 512 + lane * 8);
        const _Float16* Bg = Pb + 1 * SL;
        const _Float16* Bc = Pb + 8 * SL;
#pragma unroll
        for (int jt2 = 0; jt2 < 8; ++jt2) {
            const int jt  = (w << 3) + jt2;
            const int jb  = jt >> 1;
            const int jr  = ((jt & 1) << 4) + m16;
            const int col = (jt << 4) + m16;
            const v8h bG = *(const v8h*)(Bg + jt * 512 + lane * 8);
            const v8h bC = *(const v8h*)(Bc + jt * 512 + lane * 8);
            const v4f g4 = __builtin_amdgcn_mfma_f32_16x16x32_f16(a_g, bG, zero, 0, 0, 0);
            const v4f l4 = __builtin_amdgcn_mfma_f32_16x16x32_f16(a_c, bC, zero, 0, 0, 0);
            v4h s4, m4;
#pragma unroll
            for (int i = 0; i < 4; ++i) {
                const int rr = ((kg << 2) + i) * RS;
                const float PL  = (float)Lh[rr + col];
                const float PR  = (float)Rh[rr + col];
                const float eLb = jb ? (float)Lh[rr + (jb << 5) - 1] : 0.f;
                const float eRb = jb ? (float)Rh[rr + (jb << 5) - 1] : 0.f;
                const float eLc = jr ? (float)Lh[rr + 991 + jr] : 0.f;
                const float eRc = jr ? (float)Rh[rr + 991 + jr] : 0.f;
                const float eLbc = (jb && jr) ? (float)Lh[rr + ((jb - 1) << 5) + jr - 1] : 0.f;
                const float eRbc = (jb && jr) ? (float)Rh[rr + ((jb - 1) << 5) + jr - 1] : 0.f;
                const float SLv = 1.0f - eLb - eLc + eLbc;
                const float SRv = 1.0f - eRb - eRc + eRbc;
                const float mkv = PL * SRv + SLv * PR;
                s4[i] = (_Float16)(0.1f * g4[i] + l4[i] * mkv);
                m4[i] = (_Float16)mkv;
            }
            sc4[jt2] = s4;
            *(v4h*)(pm + ((size_t)jt << 8) + (lane << 2)) = m4;   // coalesced 8 B/lane
        }
    }
    __syncthreads();   // all scan reads complete before overwrite

    // ---- Phase 4b: write S -> Lh ----
    {
#pragma unroll
        for (int jt2 = 0; jt2 < 8; ++jt2) {
            const int col = ((((w << 3) + jt2)) << 4) + m16;
#pragma unroll
            for (int i = 0; i < 4; ++i)
                Lh[((kg << 2) + i) * RS + col] = sc4[jt2][i];
        }
    }
    __syncthreads();

    // ---- Phase 5: final softmax on S ----
#pragma unroll
    for (int r = 0; r < 2; ++r) softmax_pairs(&Lh[((w << 1) + r) * RS]);
    __syncthreads();

    // ---- Phase 6: PV via MFMA. wave = (nt = d-half, hf = j-quarter) ----
    {
        const int nt = w & 1, hf = w >> 1;
        v4f c = zero;
        const _Float16* Vb = Pb + 2 * SL + nt * 512 + lane * 8;
        const int kc0 = hf << 3;
#pragma unroll 4
        for (int kc2 = 0; kc2 < 8; ++kc2) {
            const int kc = kc0 + kc2;
            const v8h a = *(const v8h*)&Lh[m16 * RS + (kc << 5) + (kg << 3)];
            const v8h b = *(const v8h*)(Vb + (size_t)kc * 1024);
            c = __builtin_amdgcn_mfma_f32_16x16x32_f16(a, b, c, 0, 0, 0);
        }
        float* Pbuf = (float*)&Rh[0];   // Rh dead since phase-4 barrier
#pragma unroll
        for (int i = 0; i < 4; ++i) Pbuf[(w << 8) + (lane << 2) + i] = c[i];
    }
    __syncthreads();

    // ---- Epilogue: fold 4 j-quarters, coalesced d-fastest store ----
    {
        const float* Pbuf = (const float*)&Rh[0];
        const int r   = t >> 5;                    // row in tile (0..15)
        const int d   = t & 31;
        const int nt2 = d >> 4, n = d & 15;
        const int kg2 = r >> 2, i2 = r & 3;
        const int off = (kg2 << 6) + (n << 2) + i2;   // lane*4 + i
        float v = 0.f;
#pragma unroll
        for (int hf = 0; hf < 4; ++hf)
            v += Pbuf[(((hf << 1) + nt2) << 8) + off];
        const int srow = (rt << 4) + r;
        attn_pre[((size_t)(srow * 4 + (bh >> 3))) * 256 + (bh & 7) * 32 + d] = v;
    }
}

// ---------------- Kernel 2b: 32-way pmask reduction (fragment order, r8) ----------------
__global__ __launch_bounds__(256)
void cmask_reduce_kernel(const _Float16* __restrict__ pmask, float* __restrict__ cmask)
{
    __shared__ float T[16][516];
    const int rt = blockIdx.x, wh = blockIdx.y;
    const int t = threadIdx.x;
    const int w = (wh << 2) + (t >> 6);
    const int lane = t & 63, m16 = lane & 15, kg = lane >> 4;
    float acc[8][4] = {};
    const _Float16* base = pmask + (size_t)rt * 16384 + ((size_t)w << 11) + (lane << 2);
    for (int bh = 0; bh < 32; ++bh) {
        const _Float16* p = base + (size_t)bh * 1048576;
#pragma unroll
        for (int jt2 = 0; jt2 < 8; ++jt2) {
            const v4h h4 = *(const v4h*)(p + (jt2 << 8));
#pragma unroll
            for (int i = 0; i < 4; ++i) acc[jt2][i] += (float)h4[i];
        }
    }
#pragma unroll
    for (int jt2 = 0; jt2 < 8; ++jt2)
#pragma unroll
        for (int i = 0; i < 4; ++i)
            T[(kg << 2) + i][((w & 3) << 7) + (jt2 << 4) + m16] = acc[jt2][i];
    __syncthreads();
#pragma unroll
    for (int p8 = 0; p8 < 8; ++p8) {
        const int idx = (p8 << 8) + t;             // 0..2047
        const int row = idx >> 7, cq = idx & 127;
        const int c0 = (cq << 2);
        float4 o = *(const float4*)&T[row][c0];
        *(float4*)&cmask[((size_t)((rt << 4) + row) << 10) + (wh << 9) + c0] = o;
    }
}

// ---------------- Kernel 3: output projection (fp32, r8) ----------------
__global__ __launch_bounds__(256)
void outproj_kernel(const float* __restrict__ A, const float* __restrict__ W,
                    const float* __restrict__ bias, float* __restrict__ C)
{
    __shared__ float As[16][68];
    __shared__ float Bs[16][68];
    const int t  = threadIdx.x;
    const int n0 = blockIdx.x * 64;
    const int m0 = blockIdx.y * 64;
    const int tx = t & 15, ty = t >> 4;
    const int lm = t >> 2, lk = (t & 3) << 2;
    float acc[4][4] = {};
    for (int k0 = 0; k0 < 256; k0 += 16) {
        float4 av = *(const float4*)(A + (size_t)(m0 + lm) * 256 + k0 + lk);
        float4 bv = *(const float4*)(W + (size_t)(n0 + lm) * 256 + k0 + lk);
        As[lk + 0][lm] = av.x; As[lk + 1][lm] = av.y; As[lk + 2][lm] = av.z; As[lk + 3][lm] = av.w;
        Bs[lk + 0][lm] = bv.x; Bs[lk + 1][lm] = bv.y; Bs[lk + 2][lm] = bv.z; Bs[lk + 3][lm] = bv.w;
        __syncthreads();
#pragma unroll
        for (int kk = 0; kk < 16; ++kk) {
            float4 a4 = *(const float4*)&As[kk][ty << 2];
            float4 b4 = *(const float4*)&Bs[kk][tx << 2];
            float aa[4] = {a4.x, a4.y, a4.z, a4.w};
            float bb[4] = {b4.x, b4.y, b4.z, b4.w};
#pragma unroll
            for (int i = 0; i < 4; ++i)
#pragma unroll
                for (int j = 0; j < 4; ++j)
                    acc[i][j] = fmaf(aa[i], bb[j], acc[i][j]);
        }
        __syncthreads();
    }
#pragma unroll
    for (int i = 0; i < 4; ++i) {
        const int m  = m0 + (ty << 2) + i;
        const int c0 = n0 + (tx << 2);
        float4 o = make_float4(acc[i][0] + bias[c0 + 0], acc[i][1] + bias[c0 + 1],
                               acc[i][2] + bias[c0 + 2], acc[i][3] + bias[c0 + 3]);
        *(float4*)&C[(size_t)m * 256 + c0] = o;
    }
}

extern "C" void kernel_launch(void* const* d_in, const int* in_sizes, int n_in,
                              void* d_out, int out_size, void* d_ws, size_t ws_size,
                              hipStream_t stream)
{
    const float* q  = (const float*)d_in[0];
    const float* k  = (const float*)d_in[1];
    const float* v  = (const float*)d_in[2];
    const float* Wi = (const float*)d_in[3];
    const float* bi = (const float*)d_in[4];
    const float* Wo = (const float*)d_in[5];
    const float* bo = (const float*)d_in[6];

    float* out      = (float*)d_out;
    float* attn_out = out;                 // [1024,4,256]
    float* cmask    = out + 1048576;       // [1024,1024]

    _Float16* Ppack    = (_Float16*)d_ws;
    float*    attn_pre = (float*)((char*)d_ws + 18874368);
    _Float16* pmask    = (_Float16*)((char*)d_ws + 23068672);
    _Float16* X16      = (_Float16*)((char*)d_ws + 90177536);
    _Float16* W16      = (_Float16*)((char*)d_ws + 96468992);

    cvt_kernel<<<1824, 256, 0, stream>>>(q, k, v, Wi, X16, W16);
    proj_kernel<<<dim3(36, 64), 256, 0, stream>>>(X16, W16, bi, Ppack);
    attn_kernel<<<2048, 512, 0, stream>>>(Ppack, attn_pre, pmask);
    cmask_reduce_kernel<<<dim3(64, 2), 256, 0, stream>>>(pmask, cmask);
    outproj_kernel<<<dim3(4, 64), 256, 0, stream>>>(attn_pre, Wo, bo, attn_out);
}